// Round 1
// baseline (6637.416 us; speedup 1.0000x reference)
//
#include <hip/hip_runtime.h>

#define LEAKY(v) ((v) > 0.f ? (v) : 0.2f * (v))

// ======================= pos-bias MLP (961 rows, tiny) =======================
__device__ __forceinline__ void ln_relu11(float* p, const float* __restrict__ g,
                                          const float* __restrict__ b) {
  float mu = 0.f;
#pragma unroll
  for (int j = 0; j < 11; ++j) mu += p[j];
  mu *= (1.f / 11.f);
  float var = 0.f;
#pragma unroll
  for (int j = 0; j < 11; ++j) { float d = p[j] - mu; var += d * d; }
  var *= (1.f / 11.f);
  float inv = 1.f / sqrtf(var + 1e-5f);
#pragma unroll
  for (int j = 0; j < 11; ++j) {
    float v = (p[j] - mu) * inv * g[j] + b[j];
    p[j] = v > 0.f ? v : 0.f;
  }
}

__global__ void pos_mlp_kernel(
    const float* __restrict__ w0, const float* __restrict__ b0,
    const float* __restrict__ g1, const float* __restrict__ be1,
    const float* __restrict__ w1, const float* __restrict__ b1,
    const float* __restrict__ g2, const float* __restrict__ be2,
    const float* __restrict__ w2, const float* __restrict__ b2,
    const float* __restrict__ g3, const float* __restrict__ be3,
    const float* __restrict__ w3, const float* __restrict__ b3,
    float* __restrict__ pos_out) {
  int r = blockIdx.x * 256 + threadIdx.x;
  if (r >= 961) return;
  float bh = (float)(r / 31 - 15);
  float bw = (float)(r % 31 - 15);
  float p[11], q[11];
#pragma unroll
  for (int j = 0; j < 11; ++j) p[j] = bh * w0[2 * j] + bw * w0[2 * j + 1] + b0[j];
  ln_relu11(p, g1, be1);
#pragma unroll
  for (int j = 0; j < 11; ++j) {
    float s = b1[j];
#pragma unroll
    for (int k = 0; k < 11; ++k) s += p[k] * w1[j * 11 + k];
    q[j] = s;
  }
  ln_relu11(q, g2, be2);
#pragma unroll
  for (int j = 0; j < 11; ++j) {
    float s = b2[j];
#pragma unroll
    for (int k = 0; k < 11; ++k) s += q[k] * w2[j * 11 + k];
    p[j] = s;
  }
  ln_relu11(p, g3, be3);
#pragma unroll
  for (int n = 0; n < 6; ++n) {
    float s = b3[n];
#pragma unroll
    for (int k = 0; k < 11; ++k) s += p[k] * w3[n * 11 + k];
    pos_out[r * 6 + n] = s;
  }
}

// rpb[n][l][m] = mean over 2x2 of pos[rel_idx][n]   (6*256*64 elements)
__global__ void rpb_kernel(const float* __restrict__ pos, float* __restrict__ rpb) {
  int o = blockIdx.x * 256 + threadIdx.x;  // < 98304
  int n = o >> 14;
  int l = (o >> 6) & 255;
  int m = o & 63;
  int i1 = l >> 4, j1 = l & 15;
  int bi = m >> 3, bj = m & 7;
  float s = 0.f;
#pragma unroll
  for (int rh = 0; rh < 2; ++rh)
#pragma unroll
    for (int rw = 0; rw < 2; ++rw) {
      int i2 = bi * 2 + rh, j2 = bj * 2 + rw;
      int idx = (i1 - i2 + 15) * 31 + (j1 - j2 + 15);
      s += pos[idx * 6 + n];
    }
  rpb[o] = s * 0.25f;
}

// ======================= DFE stage 1: t1 = leaky(x @ W1 + b1), 180->36 ======
__global__ __launch_bounds__(256) void dfe1_kernel(const float* __restrict__ x,
                                                   const float* __restrict__ w1,
                                                   const float* __restrict__ b1,
                                                   float* __restrict__ t1) {
  __shared__ float xt[256][36];
  int t = threadIdx.x;
  int p0 = blockIdx.x * 256;
  float acc[36];
#pragma unroll
  for (int j = 0; j < 36; ++j) acc[j] = 0.f;
  for (int kc = 0; kc < 5; ++kc) {
    __syncthreads();
    for (int idx = t; idx < 256 * 36; idx += 256) {
      int px = idx / 36, ci = idx % 36;
      xt[px][ci] = x[(p0 + px) * 180 + kc * 36 + ci];
    }
    __syncthreads();
    for (int ci = 0; ci < 36; ++ci) {
      float v = xt[t][ci];
      const float* wr = &w1[(kc * 36 + ci) * 36];
#pragma unroll
      for (int j = 0; j < 36; ++j) acc[j] += v * wr[j];
    }
  }
  float* o = &t1[(p0 + t) * 36];
#pragma unroll
  for (int j = 0; j < 36; ++j) {
    float v = acc[j] + b1[j];
    o[j] = LEAKY(v);
  }
}

// ======================= DFE stage 2: 3x3 conv 36->36 + leaky ===============
__global__ __launch_bounds__(256) void dfe2_kernel(const float* __restrict__ t1,
                                                   const float* __restrict__ w2,
                                                   const float* __restrict__ b2,
                                                   float* __restrict__ t2) {
  __shared__ float halo[18][18][36];
  int t = threadIdx.x;
  int blk = blockIdx.x;
  int img = blk >> 8;
  int rem = blk & 255;
  int ty0 = (rem >> 4) << 4;
  int tx0 = (rem & 15) << 4;
  for (int idx = t; idx < 18 * 18 * 36; idx += 256) {
    int ci = idx % 36;
    int xx = (idx / 36) % 18;
    int yy = idx / (36 * 18);
    int gy = ty0 + yy - 1;
    int gx = tx0 + xx - 1;
    float v = 0.f;
    if (gy >= 0 && gy < 256 && gx >= 0 && gx < 256)
      v = t1[((img * 256 + gy) * 256 + gx) * 36 + ci];
    halo[yy][xx][ci] = v;
  }
  __syncthreads();
  int ly = t >> 4, lx = t & 15;
  float acc[36];
#pragma unroll
  for (int j = 0; j < 36; ++j) acc[j] = 0.f;
#pragma unroll
  for (int kh = 0; kh < 3; ++kh)
#pragma unroll
    for (int kw = 0; kw < 3; ++kw) {
      for (int ci = 0; ci < 36; ++ci) {
        float v = halo[ly + kh][lx + kw][ci];
        const float* wr = &w2[((kh * 3 + kw) * 36 + ci) * 36];
#pragma unroll
        for (int j = 0; j < 36; ++j) acc[j] += v * wr[j];
      }
    }
  float* o = &t2[((img * 256 + ty0 + ly) * 256 + tx0 + lx) * 36];
#pragma unroll
  for (int j = 0; j < 36; ++j) {
    float v = acc[j] + b2[j];
    o[j] = LEAKY(v);
  }
}

// ======== DFE stage 3: qv = (t2@W3 + b3) * (x@Wl + bl), tiled GEMM pair =====
__global__ __launch_bounds__(256) void dfe3_kernel(const float* __restrict__ x,
                                                   const float* __restrict__ t2,
                                                   const float* __restrict__ w3,
                                                   const float* __restrict__ b3,
                                                   const float* __restrict__ wl,
                                                   const float* __restrict__ bl,
                                                   float* __restrict__ qv) {
  __shared__ __align__(16) float At[36][68];
  __shared__ __align__(16) float Bt[36][64];
  int t = threadIdx.x;
  int tx = t & 15, ty = t >> 4;
  int mt = blockIdx.x / 3, nt = blockIdx.x % 3;
  int p0 = mt * 64, n0 = nt * 64;
  float accC[4][4], accL[4][4];
#pragma unroll
  for (int i = 0; i < 4; ++i)
#pragma unroll
    for (int j = 0; j < 4; ++j) { accC[i][j] = 0.f; accL[i][j] = 0.f; }

  // conv path: K = 36, A = t2 tile, B = W3
  for (int idx = t; idx < 64 * 36; idx += 256) {
    int px = idx / 36, ci = idx % 36;
    At[ci][px] = t2[(p0 + px) * 36 + ci];
  }
  for (int idx = t; idx < 36 * 64; idx += 256) {
    int ci = idx >> 6, co = idx & 63;
    Bt[ci][co] = (n0 + co < 180) ? w3[ci * 180 + n0 + co] : 0.f;
  }
  __syncthreads();
  for (int ci = 0; ci < 36; ++ci) {
    float4 a = *(const float4*)&At[ci][ty * 4];
    float4 b = *(const float4*)&Bt[ci][tx * 4];
    float av[4] = {a.x, a.y, a.z, a.w};
    float bv[4] = {b.x, b.y, b.z, b.w};
#pragma unroll
    for (int i = 0; i < 4; ++i)
#pragma unroll
      for (int j = 0; j < 4; ++j) accC[i][j] += av[i] * bv[j];
  }
  __syncthreads();

  // linear path: K = 180 in 5 chunks, A = x tile, B = Wl
  for (int kc = 0; kc < 5; ++kc) {
    for (int idx = t; idx < 64 * 36; idx += 256) {
      int px = idx / 36, ci = idx % 36;
      At[ci][px] = x[(p0 + px) * 180 + kc * 36 + ci];
    }
    for (int idx = t; idx < 36 * 64; idx += 256) {
      int ci = idx >> 6, co = idx & 63;
      Bt[ci][co] = (n0 + co < 180) ? wl[(kc * 36 + ci) * 180 + n0 + co] : 0.f;
    }
    __syncthreads();
    for (int ci = 0; ci < 36; ++ci) {
      float4 a = *(const float4*)&At[ci][ty * 4];
      float4 b = *(const float4*)&Bt[ci][tx * 4];
      float av[4] = {a.x, a.y, a.z, a.w};
      float bv[4] = {b.x, b.y, b.z, b.w};
#pragma unroll
      for (int i = 0; i < 4; ++i)
#pragma unroll
        for (int j = 0; j < 4; ++j) accL[i][j] += av[i] * bv[j];
    }
    __syncthreads();
  }

#pragma unroll
  for (int i = 0; i < 4; ++i) {
    int p = p0 + ty * 4 + i;
#pragma unroll
    for (int j = 0; j < 4; ++j) {
      int co = n0 + tx * 4 + j;
      if (co < 180) {
        float cp = accC[i][j] + b3[co];
        float lp = accL[i][j] + bl[co];
        qv[p * 180 + co] = cp * lp;
      }
    }
  }
}

// ========== spatial attention + first projection half (writes out) ==========
__global__ __launch_bounds__(256) void att_sp_kernel(
    const float* __restrict__ qv, const float* __restrict__ slw,
    const float* __restrict__ slb, const float* __restrict__ rpb,
    const float* __restrict__ pw, const float* __restrict__ pb,
    float* __restrict__ out) {
  __shared__ __align__(16) float vp[6][64][16];
  __shared__ float xsp[128][97];
  int t = threadIdx.x;
  int wb = blockIdx.x;
  int b = wb >> 8, wi = (wb >> 4) & 15, wj = wb & 15;
  int wbase = (b * 256 + wi * 16) * 256 + wj * 16;  // pixel index of token 0
  float wsl0 = slw[0], wsl1 = slw[1], wsl2 = slw[2], wsl3 = slw[3];
  float bsl = slb[0];

  // vp[n][m][ch] = weighted 2x2 pool of v + bias   (ch 15 zero-padded)
  for (int idx = t; idx < 6 * 64 * 16; idx += 256) {
    int n = idx >> 10;
    int m = (idx >> 4) & 63;
    int ch = idx & 15;
    float s = 0.f;
    if (ch < 15) {
      int bi = m >> 3, bj = m & 7;
      int pa00 = (wbase + (bi * 2) * 256 + bj * 2) * 180 + 90 + n * 15 + ch;
      s = qv[pa00] * wsl0;
      s += qv[pa00 + 180] * wsl1;
      s += qv[pa00 + 256 * 180] * wsl2;
      s += qv[pa00 + 257 * 180] * wsl3;
      s += bsl;
    }
    vp[n][m][ch] = s;
  }
  __syncthreads();

#pragma unroll 1
  for (int half = 0; half < 2; ++half) {
    int lt = t & 127;
    int hg = t >> 7;
    int l = half * 128 + lt;
    int pa = (wbase + (l >> 4) * 256 + (l & 15)) * 180;
#pragma unroll 1
    for (int nn = 0; nn < 3; ++nn) {
      int n = hg * 3 + nn;
      float qh[15];
#pragma unroll
      for (int c = 0; c < 15; ++c) qh[c] = qv[pa + n * 15 + c];
      float corr[64];
      const float* rp = &rpb[(n * 256 + l) * 64];
#pragma unroll
      for (int m = 0; m < 64; ++m) {
        const float4* vr = (const float4*)(&vp[n][m][0]);
        float4 v0 = vr[0], v1 = vr[1], v2 = vr[2], v3 = vr[3];
        float s = qh[0] * v0.x + qh[1] * v0.y + qh[2] * v0.z + qh[3] * v0.w +
                  qh[4] * v1.x + qh[5] * v1.y + qh[6] * v1.z + qh[7] * v1.w +
                  qh[8] * v2.x + qh[9] * v2.y + qh[10] * v2.z + qh[11] * v2.w +
                  qh[12] * v3.x + qh[13] * v3.y + qh[14] * v3.z;
        corr[m] = s * (1.f / 15.f) + rp[m];
      }
      float xs[16];
#pragma unroll
      for (int c = 0; c < 16; ++c) xs[c] = 0.f;
#pragma unroll
      for (int m = 0; m < 64; ++m) {
        const float4* vr = (const float4*)(&vp[n][m][0]);
        float4 v0 = vr[0], v1 = vr[1], v2 = vr[2], v3 = vr[3];
        float cmv = corr[m];
        xs[0] += cmv * v0.x; xs[1] += cmv * v0.y; xs[2] += cmv * v0.z; xs[3] += cmv * v0.w;
        xs[4] += cmv * v1.x; xs[5] += cmv * v1.y; xs[6] += cmv * v1.z; xs[7] += cmv * v1.w;
        xs[8] += cmv * v2.x; xs[9] += cmv * v2.y; xs[10] += cmv * v2.z; xs[11] += cmv * v2.w;
        xs[12] += cmv * v3.x; xs[13] += cmv * v3.y; xs[14] += cmv * v3.z;
      }
#pragma unroll
      for (int c = 0; c < 15; ++c) xsp[lt][n * 15 + c] = xs[c];
    }
    __syncthreads();
    // projection: out[l, k] = sum_c xsp[c] * P[k, c] + bias
    int kg = __builtin_amdgcn_readfirstlane(t >> 7);
#pragma unroll 1
    for (int kb = 0; kb < 2; ++kb) {
      int k0 = kg * 90 + kb * 45;
      float pacc[45];
#pragma unroll
      for (int j = 0; j < 45; ++j) pacc[j] = pb[k0 + j];
      for (int c = 0; c < 90; ++c) {
        float xv = xsp[lt][c];
#pragma unroll
        for (int j = 0; j < 45; ++j) pacc[j] += xv * pw[(k0 + j) * 180 + c];
      }
#pragma unroll
      for (int j = 0; j < 45; ++j) out[pa + k0 + j] = pacc[j];
    }
    __syncthreads();
  }
}

// ========== channel attention + second projection half (out +=) =============
__global__ __launch_bounds__(256) void att_ch_kernel(const float* __restrict__ qv,
                                                     const float* __restrict__ pw,
                                                     float* __restrict__ out) {
  __shared__ float vt[256][96];
  __shared__ float cmt[96][90];
  __shared__ float qs[16][96];
  __shared__ float xt[96][64];
  int t = threadIdx.x;
  int wb = blockIdx.x;
  int b = wb >> 8, wi = (wb >> 4) & 15, wj = wb & 15;
  int wbase = (b * 256 + wi * 16) * 256 + wj * 16;

  for (int idx = t; idx < 256 * 96; idx += 256) {
    int l = idx / 96, c = idx % 96;
    int pa = (wbase + (l >> 4) * 256 + (l & 15)) * 180;
    vt[l][c] = (c < 90) ? qv[pa + 90 + c] : 0.f;
  }

  int tx = t & 15, ty = t >> 4;
  float acc[6][6];
#pragma unroll
  for (int i = 0; i < 6; ++i)
#pragma unroll
    for (int j = 0; j < 6; ++j) acc[i][j] = 0.f;

  // cmap[c][d] = sum_l q[l,c] v[l,d] / 256
  for (int ck = 0; ck < 16; ++ck) {
    __syncthreads();
    for (int idx = t; idx < 16 * 96; idx += 256) {
      int l = idx / 96, c = idx % 96;
      int gl = ck * 16 + l;
      int pa = (wbase + (gl >> 4) * 256 + (gl & 15)) * 180;
      qs[l][c] = (c < 90) ? qv[pa + c] : 0.f;
    }
    __syncthreads();
    for (int lk = 0; lk < 16; ++lk) {
      float aa[6], bb[6];
#pragma unroll
      for (int i = 0; i < 6; ++i) aa[i] = qs[lk][tx * 6 + i];
#pragma unroll
      for (int j = 0; j < 6; ++j) bb[j] = vt[ck * 16 + lk][ty * 6 + j];
#pragma unroll
      for (int i = 0; i < 6; ++i)
#pragma unroll
        for (int j = 0; j < 6; ++j) acc[i][j] += aa[i] * bb[j];
    }
  }
  __syncthreads();
#pragma unroll
  for (int i = 0; i < 6; ++i)
#pragma unroll
    for (int j = 0; j < 6; ++j) {
      int d = ty * 6 + j;
      if (d < 90) cmt[tx * 6 + i][d] = acc[i][j] * (1.f / 256.f);
    }
  __syncthreads();

  // per 64-token pass: xch = cmap @ v   then   out += xch @ P2^T
#pragma unroll 1
  for (int pass = 0; pass < 4; ++pass) {
    int l0 = pass * 64;
    float xacc[4][6];
#pragma unroll
    for (int r = 0; r < 4; ++r)
#pragma unroll
      for (int i = 0; i < 6; ++i) xacc[r][i] = 0.f;
    for (int d = 0; d < 90; ++d) {
      float vv[4], cc[6];
#pragma unroll
      for (int r = 0; r < 4; ++r) vv[r] = vt[l0 + ty * 4 + r][d];
#pragma unroll
      for (int i = 0; i < 6; ++i) cc[i] = cmt[tx * 6 + i][d];
#pragma unroll
      for (int r = 0; r < 4; ++r)
#pragma unroll
        for (int i = 0; i < 6; ++i) xacc[r][i] += vv[r] * cc[i];
    }
#pragma unroll
    for (int i = 0; i < 6; ++i)
#pragma unroll
      for (int r = 0; r < 4; ++r) xt[tx * 6 + i][ty * 4 + r] = xacc[r][i];
    __syncthreads();

    int lt = t & 63;
    int kg = __builtin_amdgcn_readfirstlane(t >> 6);
    float pacc[45];
#pragma unroll
    for (int j = 0; j < 45; ++j) pacc[j] = 0.f;
    for (int c = 0; c < 90; ++c) {
      float xv = xt[c][lt];
#pragma unroll
      for (int j = 0; j < 45; ++j) pacc[j] += xv * pw[(kg * 45 + j) * 180 + 90 + c];
    }
    int gl = l0 + lt;
    int oa = (wbase + (gl >> 4) * 256 + (gl & 15)) * 180 + kg * 45;
#pragma unroll
    for (int j = 0; j < 45; ++j) out[oa + j] += pacc[j];
    __syncthreads();
  }
}

// ============================== launcher ====================================
extern "C" void kernel_launch(void* const* d_in, const int* in_sizes, int n_in,
                              void* d_out, int out_size, void* d_ws, size_t ws_size,
                              hipStream_t stream) {
  (void)in_sizes; (void)n_in; (void)out_size; (void)ws_size;
  const float* x   = (const float*)d_in[0];
  const float* w1  = (const float*)d_in[1];
  const float* b1  = (const float*)d_in[2];
  const float* w2  = (const float*)d_in[3];
  const float* b2  = (const float*)d_in[4];
  const float* w3  = (const float*)d_in[5];
  const float* b3  = (const float*)d_in[6];
  const float* wl  = (const float*)d_in[7];
  const float* bl  = (const float*)d_in[8];
  const float* slw = (const float*)d_in[9];
  const float* slb = (const float*)d_in[10];
  const float* pw0 = (const float*)d_in[11];
  const float* pb0 = (const float*)d_in[12];
  const float* g1  = (const float*)d_in[13];
  const float* be1 = (const float*)d_in[14];
  const float* mw1 = (const float*)d_in[15];
  const float* mb1 = (const float*)d_in[16];
  const float* g2  = (const float*)d_in[17];
  const float* be2 = (const float*)d_in[18];
  const float* mw2 = (const float*)d_in[19];
  const float* mb2 = (const float*)d_in[20];
  const float* g3  = (const float*)d_in[21];
  const float* be3 = (const float*)d_in[22];
  const float* mw3 = (const float*)d_in[23];
  const float* mb3 = (const float*)d_in[24];
  const float* pjw = (const float*)d_in[25];
  const float* pjb = (const float*)d_in[26];
  float* out = (float*)d_out;
  float* ws  = (float*)d_ws;

  float* qv  = ws;                      // 47185920 floats
  float* t1  = ws + 47185920;           // 9437184
  float* t2  = t1 + 9437184;            // 9437184
  float* pos = t2 + 9437184;            // 5766 (padded to 5768)
  float* rpb = pos + 5768;              // 98304

  pos_mlp_kernel<<<4, 256, 0, stream>>>(pw0, pb0, g1, be1, mw1, mb1,
                                        g2, be2, mw2, mb2, g3, be3, mw3, mb3, pos);
  rpb_kernel<<<384, 256, 0, stream>>>(pos, rpb);
  dfe1_kernel<<<1024, 256, 0, stream>>>(x, w1, b1, t1);
  dfe2_kernel<<<1024, 256, 0, stream>>>(t1, w2, b2, t2);
  dfe3_kernel<<<12288, 256, 0, stream>>>(x, t2, w3, b3, wl, bl, qv);
  att_sp_kernel<<<1024, 256, 0, stream>>>(qv, slw, slb, rpb, pjw, pjb, out);
  att_ch_kernel<<<1024, 256, 0, stream>>>(qv, pjw, out);
}

// Round 2
// 3877.094 us; speedup vs baseline: 1.7120x; 1.7120x over previous
//
#include <hip/hip_runtime.h>

#define LEAKY(v) ((v) > 0.f ? (v) : 0.2f * (v))

// ======================= pos-bias MLP (961 rows, tiny) =======================
__device__ __forceinline__ void ln_relu11(float* p, const float* __restrict__ g,
                                          const float* __restrict__ b) {
  float mu = 0.f;
#pragma unroll
  for (int j = 0; j < 11; ++j) mu += p[j];
  mu *= (1.f / 11.f);
  float var = 0.f;
#pragma unroll
  for (int j = 0; j < 11; ++j) { float d = p[j] - mu; var += d * d; }
  var *= (1.f / 11.f);
  float inv = 1.f / sqrtf(var + 1e-5f);
#pragma unroll
  for (int j = 0; j < 11; ++j) {
    float v = (p[j] - mu) * inv * g[j] + b[j];
    p[j] = v > 0.f ? v : 0.f;
  }
}

__global__ void pos_mlp_kernel(
    const float* __restrict__ w0, const float* __restrict__ b0,
    const float* __restrict__ g1, const float* __restrict__ be1,
    const float* __restrict__ w1, const float* __restrict__ b1,
    const float* __restrict__ g2, const float* __restrict__ be2,
    const float* __restrict__ w2, const float* __restrict__ b2,
    const float* __restrict__ g3, const float* __restrict__ be3,
    const float* __restrict__ w3, const float* __restrict__ b3,
    float* __restrict__ pos_out) {
  int r = blockIdx.x * 256 + threadIdx.x;
  if (r >= 961) return;
  float bh = (float)(r / 31 - 15);
  float bw = (float)(r % 31 - 15);
  float p[11], q[11];
#pragma unroll
  for (int j = 0; j < 11; ++j) p[j] = bh * w0[2 * j] + bw * w0[2 * j + 1] + b0[j];
  ln_relu11(p, g1, be1);
#pragma unroll
  for (int j = 0; j < 11; ++j) {
    float s = b1[j];
#pragma unroll
    for (int k = 0; k < 11; ++k) s += p[k] * w1[j * 11 + k];
    q[j] = s;
  }
  ln_relu11(q, g2, be2);
#pragma unroll
  for (int j = 0; j < 11; ++j) {
    float s = b2[j];
#pragma unroll
    for (int k = 0; k < 11; ++k) s += q[k] * w2[j * 11 + k];
    p[j] = s;
  }
  ln_relu11(p, g3, be3);
#pragma unroll
  for (int n = 0; n < 6; ++n) {
    float s = b3[n];
#pragma unroll
    for (int k = 0; k < 11; ++k) s += p[k] * w3[n * 11 + k];
    pos_out[r * 6 + n] = s;
  }
}

// rpb[n][l][m] = mean over 2x2 of pos[rel_idx][n]   (6*256*64 elements)
__global__ void rpb_kernel(const float* __restrict__ pos, float* __restrict__ rpb) {
  int o = blockIdx.x * 256 + threadIdx.x;  // < 98304
  int n = o >> 14;
  int l = (o >> 6) & 255;
  int m = o & 63;
  int i1 = l >> 4, j1 = l & 15;
  int bi = m >> 3, bj = m & 7;
  float s = 0.f;
#pragma unroll
  for (int rh = 0; rh < 2; ++rh)
#pragma unroll
    for (int rw = 0; rw < 2; ++rw) {
      int i2 = bi * 2 + rh, j2 = bj * 2 + rw;
      int idx = (i1 - i2 + 15) * 31 + (j1 - j2 + 15);
      s += pos[idx * 6 + n];
    }
  rpb[o] = s * 0.25f;
}

// ======================= DFE stage 1: t1 = leaky(x @ W1 + b1), 180->36 ======
__global__ __launch_bounds__(256) void dfe1_kernel(const float* __restrict__ x,
                                                   const float* __restrict__ w1,
                                                   const float* __restrict__ b1,
                                                   float* __restrict__ t1) {
  __shared__ float xt[256][36];
  int t = threadIdx.x;
  int p0 = blockIdx.x * 256;
  float acc[36];
#pragma unroll
  for (int j = 0; j < 36; ++j) acc[j] = 0.f;
  for (int kc = 0; kc < 5; ++kc) {
    __syncthreads();
    for (int idx = t; idx < 256 * 36; idx += 256) {
      int px = idx / 36, ci = idx % 36;
      xt[px][ci] = x[(p0 + px) * 180 + kc * 36 + ci];
    }
    __syncthreads();
    for (int ci = 0; ci < 36; ++ci) {
      float v = xt[t][ci];
      const float* wr = &w1[(kc * 36 + ci) * 36];
#pragma unroll
      for (int j = 0; j < 36; ++j) acc[j] += v * wr[j];
    }
  }
  float* o = &t1[(p0 + t) * 36];
#pragma unroll
  for (int j = 0; j < 36; ++j) {
    float v = acc[j] + b1[j];
    o[j] = LEAKY(v);
  }
}

// ======================= DFE stage 2: 3x3 conv 36->36 + leaky ===============
__global__ __launch_bounds__(256) void dfe2_kernel(const float* __restrict__ t1,
                                                   const float* __restrict__ w2,
                                                   const float* __restrict__ b2,
                                                   float* __restrict__ t2) {
  __shared__ float halo[18][18][36];
  int t = threadIdx.x;
  int blk = blockIdx.x;
  int img = blk >> 8;
  int rem = blk & 255;
  int ty0 = (rem >> 4) << 4;
  int tx0 = (rem & 15) << 4;
  for (int idx = t; idx < 18 * 18 * 36; idx += 256) {
    int ci = idx % 36;
    int xx = (idx / 36) % 18;
    int yy = idx / (36 * 18);
    int gy = ty0 + yy - 1;
    int gx = tx0 + xx - 1;
    float v = 0.f;
    if (gy >= 0 && gy < 256 && gx >= 0 && gx < 256)
      v = t1[((img * 256 + gy) * 256 + gx) * 36 + ci];
    halo[yy][xx][ci] = v;
  }
  __syncthreads();
  int ly = t >> 4, lx = t & 15;
  float acc[36];
#pragma unroll
  for (int j = 0; j < 36; ++j) acc[j] = 0.f;
#pragma unroll
  for (int kh = 0; kh < 3; ++kh)
#pragma unroll
    for (int kw = 0; kw < 3; ++kw) {
      for (int ci = 0; ci < 36; ++ci) {
        float v = halo[ly + kh][lx + kw][ci];
        const float* wr = &w2[((kh * 3 + kw) * 36 + ci) * 36];
#pragma unroll
        for (int j = 0; j < 36; ++j) acc[j] += v * wr[j];
      }
    }
  float* o = &t2[((img * 256 + ty0 + ly) * 256 + tx0 + lx) * 36];
#pragma unroll
  for (int j = 0; j < 36; ++j) {
    float v = acc[j] + b2[j];
    o[j] = LEAKY(v);
  }
}

// ======== DFE stage 3: qv = (t2@W3 + b3) * (x@Wl + bl), tiled GEMM pair =====
__global__ __launch_bounds__(256) void dfe3_kernel(const float* __restrict__ x,
                                                   const float* __restrict__ t2,
                                                   const float* __restrict__ w3,
                                                   const float* __restrict__ b3,
                                                   const float* __restrict__ wl,
                                                   const float* __restrict__ bl,
                                                   float* __restrict__ qv) {
  __shared__ __align__(16) float At[36][68];
  __shared__ __align__(16) float Bt[36][64];
  int t = threadIdx.x;
  int tx = t & 15, ty = t >> 4;
  int mt = blockIdx.x / 3, nt = blockIdx.x % 3;
  int p0 = mt * 64, n0 = nt * 64;
  float accC[4][4], accL[4][4];
#pragma unroll
  for (int i = 0; i < 4; ++i)
#pragma unroll
    for (int j = 0; j < 4; ++j) { accC[i][j] = 0.f; accL[i][j] = 0.f; }

  // conv path: K = 36, A = t2 tile, B = W3
  for (int idx = t; idx < 64 * 36; idx += 256) {
    int px = idx / 36, ci = idx % 36;
    At[ci][px] = t2[(p0 + px) * 36 + ci];
  }
  for (int idx = t; idx < 36 * 64; idx += 256) {
    int ci = idx >> 6, co = idx & 63;
    Bt[ci][co] = (n0 + co < 180) ? w3[ci * 180 + n0 + co] : 0.f;
  }
  __syncthreads();
  for (int ci = 0; ci < 36; ++ci) {
    float4 a = *(const float4*)&At[ci][ty * 4];
    float4 b = *(const float4*)&Bt[ci][tx * 4];
    float av[4] = {a.x, a.y, a.z, a.w};
    float bv[4] = {b.x, b.y, b.z, b.w};
#pragma unroll
    for (int i = 0; i < 4; ++i)
#pragma unroll
      for (int j = 0; j < 4; ++j) accC[i][j] += av[i] * bv[j];
  }
  __syncthreads();

  // linear path: K = 180 in 5 chunks, A = x tile, B = Wl
  for (int kc = 0; kc < 5; ++kc) {
    for (int idx = t; idx < 64 * 36; idx += 256) {
      int px = idx / 36, ci = idx % 36;
      At[ci][px] = x[(p0 + px) * 180 + kc * 36 + ci];
    }
    for (int idx = t; idx < 36 * 64; idx += 256) {
      int ci = idx >> 6, co = idx & 63;
      Bt[ci][co] = (n0 + co < 180) ? wl[(kc * 36 + ci) * 180 + n0 + co] : 0.f;
    }
    __syncthreads();
    for (int ci = 0; ci < 36; ++ci) {
      float4 a = *(const float4*)&At[ci][ty * 4];
      float4 b = *(const float4*)&Bt[ci][tx * 4];
      float av[4] = {a.x, a.y, a.z, a.w};
      float bv[4] = {b.x, b.y, b.z, b.w};
#pragma unroll
      for (int i = 0; i < 4; ++i)
#pragma unroll
        for (int j = 0; j < 4; ++j) accL[i][j] += av[i] * bv[j];
    }
    __syncthreads();
  }

#pragma unroll
  for (int i = 0; i < 4; ++i) {
    int p = p0 + ty * 4 + i;
#pragma unroll
    for (int j = 0; j < 4; ++j) {
      int co = n0 + tx * 4 + j;
      if (co < 180) {
        float cp = accC[i][j] + b3[co];
        float lp = accL[i][j] + bl[co];
        qv[p * 180 + co] = cp * lp;
      }
    }
  }
}

// ========== spatial attention + first projection half (writes out) ==========
// Per window: fused score->accumulate loop (no corr[] array), 128-token halves
// through LDS, low VGPR, 2 blocks/CU.
__global__ __launch_bounds__(256, 4) void att_sp_kernel(
    const float* __restrict__ qv, const float* __restrict__ slw,
    const float* __restrict__ slb, const float* __restrict__ rpb,
    const float* __restrict__ pw, const float* __restrict__ pb,
    float* __restrict__ out) {
  __shared__ __align__(16) float vp[6][64][16];  // 24.6 KB
  __shared__ float xsp[128][91];                 // 46.6 KB (odd stride)
  int t = threadIdx.x;
  int wb = blockIdx.x;
  int b = wb >> 8, wi = (wb >> 4) & 15, wj = wb & 15;
  int wbase = (b * 256 + wi * 16) * 256 + wj * 16;  // pixel index of token 0
  float wsl0 = slw[0], wsl1 = slw[1], wsl2 = slw[2], wsl3 = slw[3];
  float bsl = slb[0];

  // vp[n][m][ch] = weighted 2x2 pool of v + bias   (ch 15 zero-padded)
  for (int idx = t; idx < 6 * 64 * 16; idx += 256) {
    int n = idx >> 10;
    int m = (idx >> 4) & 63;
    int ch = idx & 15;
    float s = 0.f;
    if (ch < 15) {
      int bi = m >> 3, bj = m & 7;
      int pa00 = (wbase + (bi * 2) * 256 + bj * 2) * 180 + 90 + n * 15 + ch;
      s = qv[pa00] * wsl0;
      s += qv[pa00 + 180] * wsl1;
      s += qv[pa00 + 256 * 180] * wsl2;
      s += qv[pa00 + 257 * 180] * wsl3;
      s += bsl;
    }
    vp[n][m][ch] = s;
  }
  __syncthreads();

  int lt = t & 127;
  int hg = t >> 7;
  const float inv15 = 1.f / 15.f;

#pragma unroll 1
  for (int half = 0; half < 2; ++half) {
    int l = half * 128 + lt;
    int pa = (wbase + (l >> 4) * 256 + (l & 15)) * 180;
    // ---- attention: this thread handles token l, heads hg*3..hg*3+2 ----
#pragma unroll 1
    for (int nn = 0; nn < 3; ++nn) {
      int n = hg * 3 + nn;
      float qh[15];
#pragma unroll
      for (int c = 0; c < 15; ++c) qh[c] = qv[pa + n * 15 + c];
      float xs[15];
#pragma unroll
      for (int c = 0; c < 15; ++c) xs[c] = 0.f;
      const float* rp = &rpb[(n * 256 + l) * 64];
#pragma unroll 4
      for (int m4 = 0; m4 < 16; ++m4) {
        float4 rpv = *(const float4*)(rp + m4 * 4);
        float rparr[4] = {rpv.x, rpv.y, rpv.z, rpv.w};
#pragma unroll
        for (int mm = 0; mm < 4; ++mm) {
          const float4* vr = (const float4*)(&vp[n][m4 * 4 + mm][0]);
          float4 v0 = vr[0], v1 = vr[1], v2 = vr[2], v3 = vr[3];
          float s = qh[0] * v0.x + qh[1] * v0.y + qh[2] * v0.z + qh[3] * v0.w +
                    qh[4] * v1.x + qh[5] * v1.y + qh[6] * v1.z + qh[7] * v1.w +
                    qh[8] * v2.x + qh[9] * v2.y + qh[10] * v2.z + qh[11] * v2.w +
                    qh[12] * v3.x + qh[13] * v3.y + qh[14] * v3.z;
          s = s * inv15 + rparr[mm];
          xs[0] += s * v0.x; xs[1] += s * v0.y; xs[2] += s * v0.z; xs[3] += s * v0.w;
          xs[4] += s * v1.x; xs[5] += s * v1.y; xs[6] += s * v1.z; xs[7] += s * v1.w;
          xs[8] += s * v2.x; xs[9] += s * v2.y; xs[10] += s * v2.z; xs[11] += s * v2.w;
          xs[12] += s * v3.x; xs[13] += s * v3.y; xs[14] += s * v3.z;
        }
      }
#pragma unroll
      for (int c = 0; c < 15; ++c) xsp[lt][n * 15 + c] = xs[c];
    }
    __syncthreads();
    // ---- projection half: out[l, kg*90 .. +89] = xsp-row . P1 + bias ----
    int kg = __builtin_amdgcn_readfirstlane(hg);  // wave-uniform
    const float* pwb = pw + kg * 90 * 180;
#pragma unroll 1
    for (int kb = 0; kb < 6; ++kb) {
      int k0 = kb * 15;
      float pacc[15];
#pragma unroll
      for (int j = 0; j < 15; ++j) pacc[j] = pb[kg * 90 + k0 + j];
      for (int c = 0; c < 90; ++c) {
        float xv = xsp[lt][c];
#pragma unroll
        for (int j = 0; j < 15; ++j) pacc[j] += xv * pwb[(k0 + j) * 180 + c];
      }
#pragma unroll
      for (int j = 0; j < 15; ++j) out[pa + kg * 90 + k0 + j] = pacc[j];
    }
    __syncthreads();
  }
}

// ========== channel attention + second projection half (out +=) =============
// Phase A: cmap via chunked outer-product. Phase B: per-64-token xch GEMM +
// fused projection with wave-uniform k-groups. LDS 74.5 KB -> 2 blocks/CU.
__global__ __launch_bounds__(256, 4) void att_ch_kernel(const float* __restrict__ qv,
                                                        const float* __restrict__ pw,
                                                        float* __restrict__ out) {
  __shared__ float cmt[96][97];   // 37.2 KB
  __shared__ float bufA[32][97];  // 12.4 KB (q chunk / v chunk)
  __shared__ float xt[64][97];    // 24.8 KB (v chunk in phase A / xch in B)
  int t = threadIdx.x;
  int wb = blockIdx.x;
  int b = wb >> 8, wi = (wb >> 4) & 15, wj = wb & 15;
  int wbase = (b * 256 + wi * 16) * 256 + wj * 16;

  int tx = t & 15, ty = t >> 4;

  // ---- Phase A: cmap[c][d] = sum_l q[l,c] v[l,d] / 256 ----
  float acc[6][6];
#pragma unroll
  for (int i = 0; i < 6; ++i)
#pragma unroll
    for (int j = 0; j < 6; ++j) acc[i][j] = 0.f;

#pragma unroll 1
  for (int ck = 0; ck < 8; ++ck) {
    __syncthreads();
    for (int idx = t; idx < 32 * 97; idx += 256) {
      int l = idx / 97, c = idx % 97;
      int gl = ck * 32 + l;
      int pa = (wbase + (gl >> 4) * 256 + (gl & 15)) * 180;
      float qvl = (c < 90) ? qv[pa + c] : 0.f;
      float vvl = (c < 90) ? qv[pa + 90 + c] : 0.f;
      bufA[l][c] = qvl;
      xt[l][c] = vvl;
    }
    __syncthreads();
    for (int lk = 0; lk < 32; ++lk) {
      float aa[6], bb[6];
#pragma unroll
      for (int i = 0; i < 6; ++i) aa[i] = bufA[lk][tx * 6 + i];
#pragma unroll
      for (int j = 0; j < 6; ++j) bb[j] = xt[lk][ty * 6 + j];
#pragma unroll
      for (int i = 0; i < 6; ++i)
#pragma unroll
        for (int j = 0; j < 6; ++j) acc[i][j] += aa[i] * bb[j];
    }
  }
  __syncthreads();
#pragma unroll
  for (int i = 0; i < 6; ++i)
#pragma unroll
    for (int j = 0; j < 6; ++j) cmt[tx * 6 + i][ty * 6 + j] = acc[i][j] * (1.f / 256.f);
  __syncthreads();

  // ---- Phase B: per 64-token group: xch = v @ cmap^T, then out += xch @ P2^T
#pragma unroll 1
  for (int pair = 0; pair < 4; ++pair) {
#pragma unroll 1
    for (int sub = 0; sub < 2; ++sub) {
      __syncthreads();
      for (int idx = t; idx < 32 * 97; idx += 256) {
        int l = idx / 97, c = idx % 97;
        int gl = pair * 64 + sub * 32 + l;
        int pa = (wbase + (gl >> 4) * 256 + (gl & 15)) * 180;
        bufA[l][c] = (c < 90) ? qv[pa + 90 + c] : 0.f;
      }
      __syncthreads();
      // GEMM1: xch[l][c] = sum_d cmap[c][d] * v[l][d];  (2 tokens x 6 ch)/thread
      float a1[2][6];
#pragma unroll
      for (int r = 0; r < 2; ++r)
#pragma unroll
        for (int i = 0; i < 6; ++i) a1[r][i] = 0.f;
      for (int d = 0; d < 90; ++d) {
        float vv[2], cc[6];
#pragma unroll
        for (int r = 0; r < 2; ++r) vv[r] = bufA[ty * 2 + r][d];
#pragma unroll
        for (int i = 0; i < 6; ++i) cc[i] = cmt[tx * 6 + i][d];
#pragma unroll
        for (int r = 0; r < 2; ++r)
#pragma unroll
          for (int i = 0; i < 6; ++i) a1[r][i] += vv[r] * cc[i];
      }
#pragma unroll
      for (int r = 0; r < 2; ++r)
#pragma unroll
        for (int i = 0; i < 6; ++i) xt[sub * 32 + ty * 2 + r][tx * 6 + i] = a1[r][i];
    }
    __syncthreads();
    // GEMM2: lane = token (64), wave-uniform k-group of 45
    int l64 = t & 63;
    int kg = __builtin_amdgcn_readfirstlane(t >> 6);
    int gl = pair * 64 + l64;
    int pa = (wbase + (gl >> 4) * 256 + (gl & 15)) * 180;
    float pacc[45];
#pragma unroll
    for (int j = 0; j < 45; ++j) pacc[j] = 0.f;
    for (int c = 0; c < 90; ++c) {
      float xv = xt[l64][c];
#pragma unroll
      for (int j = 0; j < 45; ++j) pacc[j] += xv * pw[(kg * 45 + j) * 180 + 90 + c];
    }
#pragma unroll
    for (int j = 0; j < 45; ++j) out[pa + kg * 45 + j] += pacc[j];
  }
}

// ============================== launcher ====================================
extern "C" void kernel_launch(void* const* d_in, const int* in_sizes, int n_in,
                              void* d_out, int out_size, void* d_ws, size_t ws_size,
                              hipStream_t stream) {
  (void)in_sizes; (void)n_in; (void)out_size; (void)ws_size;
  const float* x   = (const float*)d_in[0];
  const float* w1  = (const float*)d_in[1];
  const float* b1  = (const float*)d_in[2];
  const float* w2  = (const float*)d_in[3];
  const float* b2  = (const float*)d_in[4];
  const float* w3  = (const float*)d_in[5];
  const float* b3  = (const float*)d_in[6];
  const float* wl  = (const float*)d_in[7];
  const float* bl  = (const float*)d_in[8];
  const float* slw = (const float*)d_in[9];
  const float* slb = (const float*)d_in[10];
  const float* pw0 = (const float*)d_in[11];
  const float* pb0 = (const float*)d_in[12];
  const float* g1  = (const float*)d_in[13];
  const float* be1 = (const float*)d_in[14];
  const float* mw1 = (const float*)d_in[15];
  const float* mb1 = (const float*)d_in[16];
  const float* g2  = (const float*)d_in[17];
  const float* be2 = (const float*)d_in[18];
  const float* mw2 = (const float*)d_in[19];
  const float* mb2 = (const float*)d_in[20];
  const float* g3  = (const float*)d_in[21];
  const float* be3 = (const float*)d_in[22];
  const float* mw3 = (const float*)d_in[23];
  const float* mb3 = (const float*)d_in[24];
  const float* pjw = (const float*)d_in[25];
  const float* pjb = (const float*)d_in[26];
  float* out = (float*)d_out;
  float* ws  = (float*)d_ws;

  float* qv  = ws;                      // 47185920 floats
  float* t1  = ws + 47185920;           // 9437184
  float* t2  = t1 + 9437184;            // 9437184
  float* pos = t2 + 9437184;            // 5766 (padded to 5768)
  float* rpb = pos + 5768;              // 98304

  pos_mlp_kernel<<<4, 256, 0, stream>>>(pw0, pb0, g1, be1, mw1, mb1,
                                        g2, be2, mw2, mb2, g3, be3, mw3, mb3, pos);
  rpb_kernel<<<384, 256, 0, stream>>>(pos, rpb);
  dfe1_kernel<<<1024, 256, 0, stream>>>(x, w1, b1, t1);
  dfe2_kernel<<<1024, 256, 0, stream>>>(t1, w2, b2, t2);
  dfe3_kernel<<<12288, 256, 0, stream>>>(x, t2, w3, b3, wl, bl, qv);
  att_sp_kernel<<<1024, 256, 0, stream>>>(qv, slw, slb, rpb, pjw, pjb, out);
  att_ch_kernel<<<1024, 256, 0, stream>>>(qv, pjw, out);
}

// Round 3
// 2435.583 us; speedup vs baseline: 2.7252x; 1.5919x over previous
//
#include <hip/hip_runtime.h>

#define LEAKY(v) ((v) > 0.f ? (v) : 0.2f * (v))

// ======================= pos-bias MLP (961 rows, tiny) =======================
__device__ __forceinline__ void ln_relu11(float* p, const float* __restrict__ g,
                                          const float* __restrict__ b) {
  float mu = 0.f;
#pragma unroll
  for (int j = 0; j < 11; ++j) mu += p[j];
  mu *= (1.f / 11.f);
  float var = 0.f;
#pragma unroll
  for (int j = 0; j < 11; ++j) { float d = p[j] - mu; var += d * d; }
  var *= (1.f / 11.f);
  float inv = 1.f / sqrtf(var + 1e-5f);
#pragma unroll
  for (int j = 0; j < 11; ++j) {
    float v = (p[j] - mu) * inv * g[j] + b[j];
    p[j] = v > 0.f ? v : 0.f;
  }
}

__global__ void pos_mlp_kernel(
    const float* __restrict__ w0, const float* __restrict__ b0,
    const float* __restrict__ g1, const float* __restrict__ be1,
    const float* __restrict__ w1, const float* __restrict__ b1,
    const float* __restrict__ g2, const float* __restrict__ be2,
    const float* __restrict__ w2, const float* __restrict__ b2,
    const float* __restrict__ g3, const float* __restrict__ be3,
    const float* __restrict__ w3, const float* __restrict__ b3,
    float* __restrict__ pos_out) {
  int r = blockIdx.x * 256 + threadIdx.x;
  if (r >= 961) return;
  float bh = (float)(r / 31 - 15);
  float bw = (float)(r % 31 - 15);
  float p[11], q[11];
#pragma unroll
  for (int j = 0; j < 11; ++j) p[j] = bh * w0[2 * j] + bw * w0[2 * j + 1] + b0[j];
  ln_relu11(p, g1, be1);
#pragma unroll
  for (int j = 0; j < 11; ++j) {
    float s = b1[j];
#pragma unroll
    for (int k = 0; k < 11; ++k) s += p[k] * w1[j * 11 + k];
    q[j] = s;
  }
  ln_relu11(q, g2, be2);
#pragma unroll
  for (int j = 0; j < 11; ++j) {
    float s = b2[j];
#pragma unroll
    for (int k = 0; k < 11; ++k) s += q[k] * w2[j * 11 + k];
    p[j] = s;
  }
  ln_relu11(p, g3, be3);
#pragma unroll
  for (int n = 0; n < 6; ++n) {
    float s = b3[n];
#pragma unroll
    for (int k = 0; k < 11; ++k) s += p[k] * w3[n * 11 + k];
    pos_out[r * 6 + n] = s;
  }
}

// rpb[n][l][m] = mean over 2x2 of pos[rel_idx][n]   (6*256*64 elements)
__global__ void rpb_kernel(const float* __restrict__ pos, float* __restrict__ rpb) {
  int o = blockIdx.x * 256 + threadIdx.x;  // < 98304
  int n = o >> 14;
  int l = (o >> 6) & 255;
  int m = o & 63;
  int i1 = l >> 4, j1 = l & 15;
  int bi = m >> 3, bj = m & 7;
  float s = 0.f;
#pragma unroll
  for (int rh = 0; rh < 2; ++rh)
#pragma unroll
    for (int rw = 0; rw < 2; ++rw) {
      int i2 = bi * 2 + rh, j2 = bj * 2 + rw;
      int idx = (i1 - i2 + 15) * 31 + (j1 - j2 + 15);
      s += pos[idx * 6 + n];
    }
  rpb[o] = s * 0.25f;
}

// ======================= DFE stage 1: t1 = leaky(x @ W1 + b1), 180->36 ======
__global__ __launch_bounds__(256) void dfe1_kernel(const float* __restrict__ x,
                                                   const float* __restrict__ w1,
                                                   const float* __restrict__ b1,
                                                   float* __restrict__ t1) {
  __shared__ float xt[256][36];
  int t = threadIdx.x;
  int p0 = blockIdx.x * 256;
  float acc[36];
#pragma unroll
  for (int j = 0; j < 36; ++j) acc[j] = 0.f;
  for (int kc = 0; kc < 5; ++kc) {
    __syncthreads();
    for (int idx = t; idx < 256 * 36; idx += 256) {
      int px = idx / 36, ci = idx % 36;
      xt[px][ci] = x[(p0 + px) * 180 + kc * 36 + ci];
    }
    __syncthreads();
    for (int ci = 0; ci < 36; ++ci) {
      float v = xt[t][ci];
      const float* wr = &w1[(kc * 36 + ci) * 36];
#pragma unroll
      for (int j = 0; j < 36; ++j) acc[j] += v * wr[j];
    }
  }
  float* o = &t1[(p0 + t) * 36];
#pragma unroll
  for (int j = 0; j < 36; ++j) {
    float v = acc[j] + b1[j];
    o[j] = LEAKY(v);
  }
}

// ======================= DFE stage 2: 3x3 conv 36->36 + leaky ===============
__global__ __launch_bounds__(256) void dfe2_kernel(const float* __restrict__ t1,
                                                   const float* __restrict__ w2,
                                                   const float* __restrict__ b2,
                                                   float* __restrict__ t2) {
  __shared__ float halo[18][18][36];
  int t = threadIdx.x;
  int blk = blockIdx.x;
  int img = blk >> 8;
  int rem = blk & 255;
  int ty0 = (rem >> 4) << 4;
  int tx0 = (rem & 15) << 4;
  for (int idx = t; idx < 18 * 18 * 36; idx += 256) {
    int ci = idx % 36;
    int xx = (idx / 36) % 18;
    int yy = idx / (36 * 18);
    int gy = ty0 + yy - 1;
    int gx = tx0 + xx - 1;
    float v = 0.f;
    if (gy >= 0 && gy < 256 && gx >= 0 && gx < 256)
      v = t1[((img * 256 + gy) * 256 + gx) * 36 + ci];
    halo[yy][xx][ci] = v;
  }
  __syncthreads();
  int ly = t >> 4, lx = t & 15;
  float acc[36];
#pragma unroll
  for (int j = 0; j < 36; ++j) acc[j] = 0.f;
#pragma unroll
  for (int kh = 0; kh < 3; ++kh)
#pragma unroll
    for (int kw = 0; kw < 3; ++kw) {
      for (int ci = 0; ci < 36; ++ci) {
        float v = halo[ly + kh][lx + kw][ci];
        const float* wr = &w2[((kh * 3 + kw) * 36 + ci) * 36];
#pragma unroll
        for (int j = 0; j < 36; ++j) acc[j] += v * wr[j];
      }
    }
  float* o = &t2[((img * 256 + ty0 + ly) * 256 + tx0 + lx) * 36];
#pragma unroll
  for (int j = 0; j < 36; ++j) {
    float v = acc[j] + b2[j];
    o[j] = LEAKY(v);
  }
}

// ======== DFE stage 3: qv = (t2@W3 + b3) * (x@Wl + bl) =====================
// One block = 64 pixels x 180 outputs (full N). 256 threads = 16 out-groups
// (12 each) x 16 px-groups (4 each). accC/accL in regs, 4 blocks/CU target.
__global__ __launch_bounds__(256, 4) void dfe3_kernel(const float* __restrict__ x,
                                                      const float* __restrict__ t2,
                                                      const float* __restrict__ w3,
                                                      const float* __restrict__ b3,
                                                      const float* __restrict__ wl,
                                                      const float* __restrict__ bl,
                                                      float* __restrict__ qv) {
  __shared__ __align__(16) float At[36][68];   // [ci][px], padded row
  __shared__ __align__(16) float Bt[36][192];  // [ci][co], 180 padded to 192
  int t = threadIdx.x;
  int tx = t & 15;   // output group: co = tx*12 .. +11 (tx==15 -> beyond 180)
  int ty = t >> 4;   // pixel group:  px = ty*4 .. +3
  int p0 = blockIdx.x * 64;

  float accC[4][12], accL[4][12];
#pragma unroll
  for (int r = 0; r < 4; ++r)
#pragma unroll
    for (int j = 0; j < 12; ++j) { accC[r][j] = 0.f; accL[r][j] = 0.f; }

  // ---- conv phase: A = t2 tile (K=36), B = W3 ----
  for (int idx = t; idx < 64 * 36; idx += 256) {
    int px = idx / 36, ci = idx % 36;
    At[ci][px] = t2[(p0 + px) * 36 + ci];
  }
  for (int idx = t; idx < 36 * 192; idx += 256) {
    int ci = idx / 192, co = idx % 192;
    Bt[ci][co] = (co < 180) ? w3[ci * 180 + co] : 0.f;
  }
  __syncthreads();
  for (int ci = 0; ci < 36; ++ci) {
    float4 a = *(const float4*)&At[ci][ty * 4];
    float4 b0 = *(const float4*)&Bt[ci][tx * 12];
    float4 b1 = *(const float4*)&Bt[ci][tx * 12 + 4];
    float4 b2 = *(const float4*)&Bt[ci][tx * 12 + 8];
    float av[4] = {a.x, a.y, a.z, a.w};
    float bv[12] = {b0.x, b0.y, b0.z, b0.w, b1.x, b1.y, b1.z, b1.w,
                    b2.x, b2.y, b2.z, b2.w};
#pragma unroll
    for (int r = 0; r < 4; ++r)
#pragma unroll
      for (int j = 0; j < 12; ++j) accC[r][j] += av[r] * bv[j];
  }

  // ---- linear phase: A = x tile (K=180 in 5 chunks), B = Wl ----
#pragma unroll 1
  for (int kc = 0; kc < 5; ++kc) {
    __syncthreads();
    for (int idx = t; idx < 64 * 36; idx += 256) {
      int px = idx / 36, ci = idx % 36;
      At[ci][px] = x[(p0 + px) * 180 + kc * 36 + ci];
    }
    for (int idx = t; idx < 36 * 192; idx += 256) {
      int ci = idx / 192, co = idx % 192;
      Bt[ci][co] = (co < 180) ? wl[(kc * 36 + ci) * 180 + co] : 0.f;
    }
    __syncthreads();
    for (int ci = 0; ci < 36; ++ci) {
      float4 a = *(const float4*)&At[ci][ty * 4];
      float4 b0 = *(const float4*)&Bt[ci][tx * 12];
      float4 b1 = *(const float4*)&Bt[ci][tx * 12 + 4];
      float4 b2 = *(const float4*)&Bt[ci][tx * 12 + 8];
      float av[4] = {a.x, a.y, a.z, a.w};
      float bv[12] = {b0.x, b0.y, b0.z, b0.w, b1.x, b1.y, b1.z, b1.w,
                      b2.x, b2.y, b2.z, b2.w};
#pragma unroll
      for (int r = 0; r < 4; ++r)
#pragma unroll
        for (int j = 0; j < 12; ++j) accL[r][j] += av[r] * bv[j];
    }
  }

  // ---- epilogue: qv = (conv + b3) * (lin + bl) ----
  if (tx < 15) {
#pragma unroll
    for (int r = 0; r < 4; ++r) {
      int base = (p0 + ty * 4 + r) * 180 + tx * 12;
#pragma unroll
      for (int j = 0; j < 12; ++j) {
        int co = tx * 12 + j;
        float cp = accC[r][j] + b3[co];
        float lp = accL[r][j] + bl[co];
        qv[base + j] = cp * lp;
      }
    }
  }
}

// ========== spatial attention + first projection half (writes out) ==========
__global__ __launch_bounds__(256, 4) void att_sp_kernel(
    const float* __restrict__ qv, const float* __restrict__ slw,
    const float* __restrict__ slb, const float* __restrict__ rpb,
    const float* __restrict__ pw, const float* __restrict__ pb,
    float* __restrict__ out) {
  __shared__ __align__(16) float vp[6][64][16];  // 24.6 KB
  __shared__ float xsp[128][91];                 // 46.6 KB (odd stride)
  int t = threadIdx.x;
  int wb = blockIdx.x;
  int b = wb >> 8, wi = (wb >> 4) & 15, wj = wb & 15;
  int wbase = (b * 256 + wi * 16) * 256 + wj * 16;  // pixel index of token 0
  float wsl0 = slw[0], wsl1 = slw[1], wsl2 = slw[2], wsl3 = slw[3];
  float bsl = slb[0];

  // vp[n][m][ch] = weighted 2x2 pool of v + bias   (ch 15 zero-padded)
  for (int idx = t; idx < 6 * 64 * 16; idx += 256) {
    int n = idx >> 10;
    int m = (idx >> 4) & 63;
    int ch = idx & 15;
    float s = 0.f;
    if (ch < 15) {
      int bi = m >> 3, bj = m & 7;
      int pa00 = (wbase + (bi * 2) * 256 + bj * 2) * 180 + 90 + n * 15 + ch;
      s = qv[pa00] * wsl0;
      s += qv[pa00 + 180] * wsl1;
      s += qv[pa00 + 256 * 180] * wsl2;
      s += qv[pa00 + 257 * 180] * wsl3;
      s += bsl;
    }
    vp[n][m][ch] = s;
  }
  __syncthreads();

  int lt = t & 127;
  int hg = t >> 7;
  const float inv15 = 1.f / 15.f;

#pragma unroll 1
  for (int half = 0; half < 2; ++half) {
    int l = half * 128 + lt;
    int pa = (wbase + (l >> 4) * 256 + (l & 15)) * 180;
    // ---- attention: this thread handles token l, heads hg*3..hg*3+2 ----
#pragma unroll 1
    for (int nn = 0; nn < 3; ++nn) {
      int n = hg * 3 + nn;
      float qh[15];
#pragma unroll
      for (int c = 0; c < 15; ++c) qh[c] = qv[pa + n * 15 + c];
      float xs[15];
#pragma unroll
      for (int c = 0; c < 15; ++c) xs[c] = 0.f;
      const float* rp = &rpb[(n * 256 + l) * 64];
#pragma unroll 4
      for (int m4 = 0; m4 < 16; ++m4) {
        float4 rpv = *(const float4*)(rp + m4 * 4);
        float rparr[4] = {rpv.x, rpv.y, rpv.z, rpv.w};
#pragma unroll
        for (int mm = 0; mm < 4; ++mm) {
          const float4* vr = (const float4*)(&vp[n][m4 * 4 + mm][0]);
          float4 v0 = vr[0], v1 = vr[1], v2 = vr[2], v3 = vr[3];
          float s = qh[0] * v0.x + qh[1] * v0.y + qh[2] * v0.z + qh[3] * v0.w +
                    qh[4] * v1.x + qh[5] * v1.y + qh[6] * v1.z + qh[7] * v1.w +
                    qh[8] * v2.x + qh[9] * v2.y + qh[10] * v2.z + qh[11] * v2.w +
                    qh[12] * v3.x + qh[13] * v3.y + qh[14] * v3.z;
          s = s * inv15 + rparr[mm];
          xs[0] += s * v0.x; xs[1] += s * v0.y; xs[2] += s * v0.z; xs[3] += s * v0.w;
          xs[4] += s * v1.x; xs[5] += s * v1.y; xs[6] += s * v1.z; xs[7] += s * v1.w;
          xs[8] += s * v2.x; xs[9] += s * v2.y; xs[10] += s * v2.z; xs[11] += s * v2.w;
          xs[12] += s * v3.x; xs[13] += s * v3.y; xs[14] += s * v3.z;
        }
      }
#pragma unroll
      for (int c = 0; c < 15; ++c) xsp[lt][n * 15 + c] = xs[c];
    }
    __syncthreads();
    // ---- projection half: out[l, kg*90 .. +89] = xsp-row . P1 + bias ----
    int kg = __builtin_amdgcn_readfirstlane(hg);  // wave-uniform
    const float* pwb = pw + kg * 90 * 180;
#pragma unroll 1
    for (int kb = 0; kb < 6; ++kb) {
      int k0 = kb * 15;
      float pacc[15];
#pragma unroll
      for (int j = 0; j < 15; ++j) pacc[j] = pb[kg * 90 + k0 + j];
      for (int c = 0; c < 90; ++c) {
        float xv = xsp[lt][c];
#pragma unroll
        for (int j = 0; j < 15; ++j) pacc[j] += xv * pwb[(k0 + j) * 180 + c];
      }
#pragma unroll
      for (int j = 0; j < 15; ++j) out[pa + kg * 90 + k0 + j] = pacc[j];
    }
    __syncthreads();
  }
}

// ========== channel attention + second projection half (out +=) =============
__global__ __launch_bounds__(256, 4) void att_ch_kernel(const float* __restrict__ qv,
                                                        const float* __restrict__ pw,
                                                        float* __restrict__ out) {
  __shared__ float cmt[96][97];   // 37.2 KB
  __shared__ float bufA[32][97];  // 12.4 KB (q chunk / v chunk)
  __shared__ float xt[64][97];    // 24.8 KB (v chunk in phase A / xch in B)
  int t = threadIdx.x;
  int wb = blockIdx.x;
  int b = wb >> 8, wi = (wb >> 4) & 15, wj = wb & 15;
  int wbase = (b * 256 + wi * 16) * 256 + wj * 16;

  int tx = t & 15, ty = t >> 4;

  // ---- Phase A: cmap[c][d] = sum_l q[l,c] v[l,d] / 256 ----
  float acc[6][6];
#pragma unroll
  for (int i = 0; i < 6; ++i)
#pragma unroll
    for (int j = 0; j < 6; ++j) acc[i][j] = 0.f;

#pragma unroll 1
  for (int ck = 0; ck < 8; ++ck) {
    __syncthreads();
    for (int idx = t; idx < 32 * 97; idx += 256) {
      int l = idx / 97, c = idx % 97;
      int gl = ck * 32 + l;
      int pa = (wbase + (gl >> 4) * 256 + (gl & 15)) * 180;
      float qvl = (c < 90) ? qv[pa + c] : 0.f;
      float vvl = (c < 90) ? qv[pa + 90 + c] : 0.f;
      bufA[l][c] = qvl;
      xt[l][c] = vvl;
    }
    __syncthreads();
    for (int lk = 0; lk < 32; ++lk) {
      float aa[6], bb[6];
#pragma unroll
      for (int i = 0; i < 6; ++i) aa[i] = bufA[lk][tx * 6 + i];
#pragma unroll
      for (int j = 0; j < 6; ++j) bb[j] = xt[lk][ty * 6 + j];
#pragma unroll
      for (int i = 0; i < 6; ++i)
#pragma unroll
        for (int j = 0; j < 6; ++j) acc[i][j] += aa[i] * bb[j];
    }
  }
  __syncthreads();
#pragma unroll
  for (int i = 0; i < 6; ++i)
#pragma unroll
    for (int j = 0; j < 6; ++j) cmt[tx * 6 + i][ty * 6 + j] = acc[i][j] * (1.f / 256.f);
  __syncthreads();

  // ---- Phase B: per 64-token group: xch = v @ cmap^T, then out += xch @ P2^T
#pragma unroll 1
  for (int pair = 0; pair < 4; ++pair) {
#pragma unroll 1
    for (int sub = 0; sub < 2; ++sub) {
      __syncthreads();
      for (int idx = t; idx < 32 * 97; idx += 256) {
        int l = idx / 97, c = idx % 97;
        int gl = pair * 64 + sub * 32 + l;
        int pa = (wbase + (gl >> 4) * 256 + (gl & 15)) * 180;
        bufA[l][c] = (c < 90) ? qv[pa + 90 + c] : 0.f;
      }
      __syncthreads();
      // GEMM1: xch[l][c] = sum_d cmap[c][d] * v[l][d];  (2 tokens x 6 ch)/thread
      float a1[2][6];
#pragma unroll
      for (int r = 0; r < 2; ++r)
#pragma unroll
        for (int i = 0; i < 6; ++i) a1[r][i] = 0.f;
      for (int d = 0; d < 90; ++d) {
        float vv[2], cc[6];
#pragma unroll
        for (int r = 0; r < 2; ++r) vv[r] = bufA[ty * 2 + r][d];
#pragma unroll
        for (int i = 0; i < 6; ++i) cc[i] = cmt[tx * 6 + i][d];
#pragma unroll
        for (int r = 0; r < 2; ++r)
#pragma unroll
          for (int i = 0; i < 6; ++i) a1[r][i] += vv[r] * cc[i];
      }
#pragma unroll
      for (int r = 0; r < 2; ++r)
#pragma unroll
        for (int i = 0; i < 6; ++i) xt[sub * 32 + ty * 2 + r][tx * 6 + i] = a1[r][i];
    }
    __syncthreads();
    // GEMM2: lane = token (64), wave-uniform k-group of 45
    int l64 = t & 63;
    int kg = __builtin_amdgcn_readfirstlane(t >> 6);
    int gl = pair * 64 + l64;
    int pa = (wbase + (gl >> 4) * 256 + (gl & 15)) * 180;
    float pacc[45];
#pragma unroll
    for (int j = 0; j < 45; ++j) pacc[j] = 0.f;
    for (int c = 0; c < 90; ++c) {
      float xv = xt[l64][c];
#pragma unroll
      for (int j = 0; j < 45; ++j) pacc[j] += xv * pw[(kg * 45 + j) * 180 + 90 + c];
    }
#pragma unroll
    for (int j = 0; j < 45; ++j) out[pa + kg * 45 + j] += pacc[j];
  }
}

// ============================== launcher ====================================
extern "C" void kernel_launch(void* const* d_in, const int* in_sizes, int n_in,
                              void* d_out, int out_size, void* d_ws, size_t ws_size,
                              hipStream_t stream) {
  (void)in_sizes; (void)n_in; (void)out_size; (void)ws_size;
  const float* x   = (const float*)d_in[0];
  const float* w1  = (const float*)d_in[1];
  const float* b1  = (const float*)d_in[2];
  const float* w2  = (const float*)d_in[3];
  const float* b2  = (const float*)d_in[4];
  const float* w3  = (const float*)d_in[5];
  const float* b3  = (const float*)d_in[6];
  const float* wl  = (const float*)d_in[7];
  const float* bl  = (const float*)d_in[8];
  const float* slw = (const float*)d_in[9];
  const float* slb = (const float*)d_in[10];
  const float* pw0 = (const float*)d_in[11];
  const float* pb0 = (const float*)d_in[12];
  const float* g1  = (const float*)d_in[13];
  const float* be1 = (const float*)d_in[14];
  const float* mw1 = (const float*)d_in[15];
  const float* mb1 = (const float*)d_in[16];
  const float* g2  = (const float*)d_in[17];
  const float* be2 = (const float*)d_in[18];
  const float* mw2 = (const float*)d_in[19];
  const float* mb2 = (const float*)d_in[20];
  const float* g3  = (const float*)d_in[21];
  const float* be3 = (const float*)d_in[22];
  const float* mw3 = (const float*)d_in[23];
  const float* mb3 = (const float*)d_in[24];
  const float* pjw = (const float*)d_in[25];
  const float* pjb = (const float*)d_in[26];
  float* out = (float*)d_out;
  float* ws  = (float*)d_ws;

  float* qv  = ws;                      // 47185920 floats
  float* t1  = ws + 47185920;           // 9437184
  float* t2  = t1 + 9437184;            // 9437184
  float* pos = t2 + 9437184;            // 5766 (padded to 5768)
  float* rpb = pos + 5768;              // 98304

  pos_mlp_kernel<<<4, 256, 0, stream>>>(pw0, pb0, g1, be1, mw1, mb1,
                                        g2, be2, mw2, mb2, g3, be3, mw3, mb3, pos);
  rpb_kernel<<<384, 256, 0, stream>>>(pos, rpb);
  dfe1_kernel<<<1024, 256, 0, stream>>>(x, w1, b1, t1);
  dfe2_kernel<<<1024, 256, 0, stream>>>(t1, w2, b2, t2);
  dfe3_kernel<<<4096, 256, 0, stream>>>(x, t2, w3, b3, wl, bl, qv);
  att_sp_kernel<<<1024, 256, 0, stream>>>(qv, slw, slb, rpb, pjw, pjb, out);
  att_ch_kernel<<<1024, 256, 0, stream>>>(qv, pjw, out);
}

// Round 4
// 1737.191 us; speedup vs baseline: 3.8208x; 1.4020x over previous
//
#include <hip/hip_runtime.h>

#define LEAKY(v) ((v) > 0.f ? (v) : 0.2f * (v))

// ======================= pos-bias MLP (961 rows, tiny) =======================
__device__ __forceinline__ void ln_relu11(float* p, const float* __restrict__ g,
                                          const float* __restrict__ b) {
  float mu = 0.f;
#pragma unroll
  for (int j = 0; j < 11; ++j) mu += p[j];
  mu *= (1.f / 11.f);
  float var = 0.f;
#pragma unroll
  for (int j = 0; j < 11; ++j) { float d = p[j] - mu; var += d * d; }
  var *= (1.f / 11.f);
  float inv = 1.f / sqrtf(var + 1e-5f);
#pragma unroll
  for (int j = 0; j < 11; ++j) {
    float v = (p[j] - mu) * inv * g[j] + b[j];
    p[j] = v > 0.f ? v : 0.f;
  }
}

__global__ void pos_mlp_kernel(
    const float* __restrict__ w0, const float* __restrict__ b0,
    const float* __restrict__ g1, const float* __restrict__ be1,
    const float* __restrict__ w1, const float* __restrict__ b1,
    const float* __restrict__ g2, const float* __restrict__ be2,
    const float* __restrict__ w2, const float* __restrict__ b2,
    const float* __restrict__ g3, const float* __restrict__ be3,
    const float* __restrict__ w3, const float* __restrict__ b3,
    float* __restrict__ pos_out) {
  int r = blockIdx.x * 256 + threadIdx.x;
  if (r >= 961) return;
  float bh = (float)(r / 31 - 15);
  float bw = (float)(r % 31 - 15);
  float p[11], q[11];
#pragma unroll
  for (int j = 0; j < 11; ++j) p[j] = bh * w0[2 * j] + bw * w0[2 * j + 1] + b0[j];
  ln_relu11(p, g1, be1);
#pragma unroll
  for (int j = 0; j < 11; ++j) {
    float s = b1[j];
#pragma unroll
    for (int k = 0; k < 11; ++k) s += p[k] * w1[j * 11 + k];
    q[j] = s;
  }
  ln_relu11(q, g2, be2);
#pragma unroll
  for (int j = 0; j < 11; ++j) {
    float s = b2[j];
#pragma unroll
    for (int k = 0; k < 11; ++k) s += q[k] * w2[j * 11 + k];
    p[j] = s;
  }
  ln_relu11(p, g3, be3);
#pragma unroll
  for (int n = 0; n < 6; ++n) {
    float s = b3[n];
#pragma unroll
    for (int k = 0; k < 11; ++k) s += p[k] * w3[n * 11 + k];
    pos_out[r * 6 + n] = s;
  }
}

// rpb[n][l][m] = mean over 2x2 of pos[rel_idx][n]   (6*256*64 elements)
__global__ void rpb_kernel(const float* __restrict__ pos, float* __restrict__ rpb) {
  int o = blockIdx.x * 256 + threadIdx.x;  // < 98304
  int n = o >> 14;
  int l = (o >> 6) & 255;
  int m = o & 63;
  int i1 = l >> 4, j1 = l & 15;
  int bi = m >> 3, bj = m & 7;
  float s = 0.f;
#pragma unroll
  for (int rh = 0; rh < 2; ++rh)
#pragma unroll
    for (int rw = 0; rw < 2; ++rw) {
      int i2 = bi * 2 + rh, j2 = bj * 2 + rw;
      int idx = (i1 - i2 + 15) * 31 + (j1 - j2 + 15);
      s += pos[idx * 6 + n];
    }
  rpb[o] = s * 0.25f;
}

// p2t[c][k] = proj_w[k][90+c]  (transposed channel-half of P, 90x180)
__global__ void p2t_kernel(const float* __restrict__ pjw, float* __restrict__ p2t) {
  int i = blockIdx.x * 256 + threadIdx.x;
  if (i >= 90 * 180) return;
  int c = i / 180, k = i % 180;
  p2t[c * 180 + k] = pjw[k * 180 + 90 + c];
}

// ======================= DFE stage 1: t1 = leaky(x @ W1 + b1), 180->36 ======
__global__ __launch_bounds__(256) void dfe1_kernel(const float* __restrict__ x,
                                                   const float* __restrict__ w1,
                                                   const float* __restrict__ b1,
                                                   float* __restrict__ t1) {
  __shared__ float xt[256][36];
  int t = threadIdx.x;
  int p0 = blockIdx.x * 256;
  float acc[36];
#pragma unroll
  for (int j = 0; j < 36; ++j) acc[j] = 0.f;
  for (int kc = 0; kc < 5; ++kc) {
    __syncthreads();
    for (int idx = t; idx < 256 * 36; idx += 256) {
      int px = idx / 36, ci = idx % 36;
      xt[px][ci] = x[(p0 + px) * 180 + kc * 36 + ci];
    }
    __syncthreads();
    for (int ci = 0; ci < 36; ++ci) {
      float v = xt[t][ci];
      const float* wr = &w1[(kc * 36 + ci) * 36];
#pragma unroll
      for (int j = 0; j < 36; ++j) acc[j] += v * wr[j];
    }
  }
  float* o = &t1[(p0 + t) * 36];
#pragma unroll
  for (int j = 0; j < 36; ++j) {
    float v = acc[j] + b1[j];
    o[j] = LEAKY(v);
  }
}

// ======================= DFE stage 2: 3x3 conv 36->36 + leaky ===============
__global__ __launch_bounds__(256) void dfe2_kernel(const float* __restrict__ t1,
                                                   const float* __restrict__ w2,
                                                   const float* __restrict__ b2,
                                                   float* __restrict__ t2) {
  __shared__ float halo[18][18][36];
  int t = threadIdx.x;
  int blk = blockIdx.x;
  int img = blk >> 8;
  int rem = blk & 255;
  int ty0 = (rem >> 4) << 4;
  int tx0 = (rem & 15) << 4;
  for (int idx = t; idx < 18 * 18 * 36; idx += 256) {
    int ci = idx % 36;
    int xx = (idx / 36) % 18;
    int yy = idx / (36 * 18);
    int gy = ty0 + yy - 1;
    int gx = tx0 + xx - 1;
    float v = 0.f;
    if (gy >= 0 && gy < 256 && gx >= 0 && gx < 256)
      v = t1[((img * 256 + gy) * 256 + gx) * 36 + ci];
    halo[yy][xx][ci] = v;
  }
  __syncthreads();
  int ly = t >> 4, lx = t & 15;
  float acc[36];
#pragma unroll
  for (int j = 0; j < 36; ++j) acc[j] = 0.f;
#pragma unroll
  for (int kh = 0; kh < 3; ++kh)
#pragma unroll
    for (int kw = 0; kw < 3; ++kw) {
      for (int ci = 0; ci < 36; ++ci) {
        float v = halo[ly + kh][lx + kw][ci];
        const float* wr = &w2[((kh * 3 + kw) * 36 + ci) * 36];
#pragma unroll
        for (int j = 0; j < 36; ++j) acc[j] += v * wr[j];
      }
    }
  float* o = &t2[((img * 256 + ty0 + ly) * 256 + tx0 + lx) * 36];
#pragma unroll
  for (int j = 0; j < 36; ++j) {
    float v = acc[j] + b2[j];
    o[j] = LEAKY(v);
  }
}

// ======== DFE stage 3: qv = (t2@W3 + b3) * (x@Wl + bl) =====================
__global__ __launch_bounds__(256, 4) void dfe3_kernel(const float* __restrict__ x,
                                                      const float* __restrict__ t2,
                                                      const float* __restrict__ w3,
                                                      const float* __restrict__ b3,
                                                      const float* __restrict__ wl,
                                                      const float* __restrict__ bl,
                                                      float* __restrict__ qv) {
  __shared__ __align__(16) float At[36][68];   // [ci][px], padded row
  __shared__ __align__(16) float Bt[36][192];  // [ci][co], 180 padded to 192
  int t = threadIdx.x;
  int tx = t & 15;   // output group: co = tx*12 .. +11 (tx==15 -> beyond 180)
  int ty = t >> 4;   // pixel group:  px = ty*4 .. +3
  int p0 = blockIdx.x * 64;

  float accC[4][12], accL[4][12];
#pragma unroll
  for (int r = 0; r < 4; ++r)
#pragma unroll
    for (int j = 0; j < 12; ++j) { accC[r][j] = 0.f; accL[r][j] = 0.f; }

  // ---- conv phase: A = t2 tile (K=36), B = W3 ----
  for (int idx = t; idx < 64 * 36; idx += 256) {
    int px = idx / 36, ci = idx % 36;
    At[ci][px] = t2[(p0 + px) * 36 + ci];
  }
  for (int idx = t; idx < 36 * 192; idx += 256) {
    int ci = idx / 192, co = idx % 192;
    Bt[ci][co] = (co < 180) ? w3[ci * 180 + co] : 0.f;
  }
  __syncthreads();
  for (int ci = 0; ci < 36; ++ci) {
    float4 a = *(const float4*)&At[ci][ty * 4];
    float4 b0 = *(const float4*)&Bt[ci][tx * 12];
    float4 b1 = *(const float4*)&Bt[ci][tx * 12 + 4];
    float4 b2 = *(const float4*)&Bt[ci][tx * 12 + 8];
    float av[4] = {a.x, a.y, a.z, a.w};
    float bv[12] = {b0.x, b0.y, b0.z, b0.w, b1.x, b1.y, b1.z, b1.w,
                    b2.x, b2.y, b2.z, b2.w};
#pragma unroll
    for (int r = 0; r < 4; ++r)
#pragma unroll
      for (int j = 0; j < 12; ++j) accC[r][j] += av[r] * bv[j];
  }

  // ---- linear phase: A = x tile (K=180 in 5 chunks), B = Wl ----
#pragma unroll 1
  for (int kc = 0; kc < 5; ++kc) {
    __syncthreads();
    for (int idx = t; idx < 64 * 36; idx += 256) {
      int px = idx / 36, ci = idx % 36;
      At[ci][px] = x[(p0 + px) * 180 + kc * 36 + ci];
    }
    for (int idx = t; idx < 36 * 192; idx += 256) {
      int ci = idx / 192, co = idx % 192;
      Bt[ci][co] = (co < 180) ? wl[(kc * 36 + ci) * 180 + co] : 0.f;
    }
    __syncthreads();
    for (int ci = 0; ci < 36; ++ci) {
      float4 a = *(const float4*)&At[ci][ty * 4];
      float4 b0 = *(const float4*)&Bt[ci][tx * 12];
      float4 b1 = *(const float4*)&Bt[ci][tx * 12 + 4];
      float4 b2 = *(const float4*)&Bt[ci][tx * 12 + 8];
      float av[4] = {a.x, a.y, a.z, a.w};
      float bv[12] = {b0.x, b0.y, b0.z, b0.w, b1.x, b1.y, b1.z, b1.w,
                      b2.x, b2.y, b2.z, b2.w};
#pragma unroll
      for (int r = 0; r < 4; ++r)
#pragma unroll
        for (int j = 0; j < 12; ++j) accL[r][j] += av[r] * bv[j];
    }
  }

  // ---- epilogue: qv = (conv + b3) * (lin + bl) ----
  if (tx < 15) {
#pragma unroll
    for (int r = 0; r < 4; ++r) {
      int base = (p0 + ty * 4 + r) * 180 + tx * 12;
#pragma unroll
      for (int j = 0; j < 12; ++j) {
        int co = tx * 12 + j;
        float cp = accC[r][j] + b3[co];
        float lp = accL[r][j] + bl[co];
        qv[base + j] = cp * lp;
      }
    }
  }
}

// ========== spatial attention + first projection half (writes out) ==========
__global__ __launch_bounds__(256, 4) void att_sp_kernel(
    const float* __restrict__ qv, const float* __restrict__ slw,
    const float* __restrict__ slb, const float* __restrict__ rpb,
    const float* __restrict__ pw, const float* __restrict__ pb,
    float* __restrict__ out) {
  __shared__ __align__(16) float vp[6][64][16];  // 24.6 KB
  __shared__ float xsp[128][91];                 // 46.6 KB (odd stride)
  int t = threadIdx.x;
  int wb = blockIdx.x;
  int b = wb >> 8, wi = (wb >> 4) & 15, wj = wb & 15;
  int wbase = (b * 256 + wi * 16) * 256 + wj * 16;  // pixel index of token 0
  float wsl0 = slw[0], wsl1 = slw[1], wsl2 = slw[2], wsl3 = slw[3];
  float bsl = slb[0];

  // vp[n][m][ch] = weighted 2x2 pool of v + bias   (ch 15 zero-padded)
  for (int idx = t; idx < 6 * 64 * 16; idx += 256) {
    int n = idx >> 10;
    int m = (idx >> 4) & 63;
    int ch = idx & 15;
    float s = 0.f;
    if (ch < 15) {
      int bi = m >> 3, bj = m & 7;
      int pa00 = (wbase + (bi * 2) * 256 + bj * 2) * 180 + 90 + n * 15 + ch;
      s = qv[pa00] * wsl0;
      s += qv[pa00 + 180] * wsl1;
      s += qv[pa00 + 256 * 180] * wsl2;
      s += qv[pa00 + 257 * 180] * wsl3;
      s += bsl;
    }
    vp[n][m][ch] = s;
  }
  __syncthreads();

  int lt = t & 127;
  int hg = t >> 7;
  const float inv15 = 1.f / 15.f;

#pragma unroll 1
  for (int half = 0; half < 2; ++half) {
    int l = half * 128 + lt;
    int pa = (wbase + (l >> 4) * 256 + (l & 15)) * 180;
    // ---- attention: this thread handles token l, heads hg*3..hg*3+2 ----
#pragma unroll 1
    for (int nn = 0; nn < 3; ++nn) {
      int n = hg * 3 + nn;
      float qh[15];
#pragma unroll
      for (int c = 0; c < 15; ++c) qh[c] = qv[pa + n * 15 + c];
      float xs[15];
#pragma unroll
      for (int c = 0; c < 15; ++c) xs[c] = 0.f;
      const float* rp = &rpb[(n * 256 + l) * 64];
#pragma unroll 4
      for (int m4 = 0; m4 < 16; ++m4) {
        float4 rpv = *(const float4*)(rp + m4 * 4);
        float rparr[4] = {rpv.x, rpv.y, rpv.z, rpv.w};
#pragma unroll
        for (int mm = 0; mm < 4; ++mm) {
          const float4* vr = (const float4*)(&vp[n][m4 * 4 + mm][0]);
          float4 v0 = vr[0], v1 = vr[1], v2 = vr[2], v3 = vr[3];
          float s = qh[0] * v0.x + qh[1] * v0.y + qh[2] * v0.z + qh[3] * v0.w +
                    qh[4] * v1.x + qh[5] * v1.y + qh[6] * v1.z + qh[7] * v1.w +
                    qh[8] * v2.x + qh[9] * v2.y + qh[10] * v2.z + qh[11] * v2.w +
                    qh[12] * v3.x + qh[13] * v3.y + qh[14] * v3.z;
          s = s * inv15 + rparr[mm];
          xs[0] += s * v0.x; xs[1] += s * v0.y; xs[2] += s * v0.z; xs[3] += s * v0.w;
          xs[4] += s * v1.x; xs[5] += s * v1.y; xs[6] += s * v1.z; xs[7] += s * v1.w;
          xs[8] += s * v2.x; xs[9] += s * v2.y; xs[10] += s * v2.z; xs[11] += s * v2.w;
          xs[12] += s * v3.x; xs[13] += s * v3.y; xs[14] += s * v3.z;
        }
      }
#pragma unroll
      for (int c = 0; c < 15; ++c) xsp[lt][n * 15 + c] = xs[c];
    }
    __syncthreads();
    // ---- projection half: out[l, kg*90 .. +89] = xsp-row . P1 + bias ----
    int kg = __builtin_amdgcn_readfirstlane(hg);  // wave-uniform
    const float* pwb = pw + kg * 90 * 180;
#pragma unroll 1
    for (int kb = 0; kb < 6; ++kb) {
      int k0 = kb * 15;
      float pacc[15];
#pragma unroll
      for (int j = 0; j < 15; ++j) pacc[j] = pb[kg * 90 + k0 + j];
      for (int c = 0; c < 90; ++c) {
        float xv = xsp[lt][c];
#pragma unroll
        for (int j = 0; j < 15; ++j) pacc[j] += xv * pwb[(k0 + j) * 180 + c];
      }
#pragma unroll
      for (int j = 0; j < 15; ++j) out[pa + kg * 90 + k0 + j] = pacc[j];
    }
    __syncthreads();
  }
}

// ========== channel attention A: cmap then M = P2*cmap per window ===========
// Phase 1: cmap[c][d] = sum_l q[l,c] v[l,d] / 256 (into LDS).
// Phase 2: M[d][k] = sum_c p2t[c][k] * cmap[c][d]  (wave-uniform k-block,
//          contiguous s_loads of p2t row; each lane owns d and d+64).
__global__ __launch_bounds__(256, 2) void cmapM_kernel(const float* __restrict__ qv,
                                                       const float* __restrict__ p2t,
                                                       float* __restrict__ M) {
  __shared__ float cmt[90][91];   // 32.8 KB
  __shared__ float bufA[32][97];  // 12.4 KB
  __shared__ float vtt[32][97];   // 12.4 KB
  int t = threadIdx.x;
  int wb = blockIdx.x;
  int b = wb >> 8, wi = (wb >> 4) & 15, wj = wb & 15;
  int wbase = (b * 256 + wi * 16) * 256 + wj * 16;

  int tx = t & 15, ty = t >> 4;
  float acc[6][6];
#pragma unroll
  for (int i = 0; i < 6; ++i)
#pragma unroll
    for (int j = 0; j < 6; ++j) acc[i][j] = 0.f;

#pragma unroll 1
  for (int ck = 0; ck < 8; ++ck) {
    __syncthreads();
    for (int idx = t; idx < 32 * 97; idx += 256) {
      int l = idx / 97, c = idx % 97;
      int gl = ck * 32 + l;
      int pa = (wbase + (gl >> 4) * 256 + (gl & 15)) * 180;
      bufA[l][c] = (c < 90) ? qv[pa + c] : 0.f;
      vtt[l][c] = (c < 90) ? qv[pa + 90 + c] : 0.f;
    }
    __syncthreads();
    for (int lk = 0; lk < 32; ++lk) {
      float aa[6], bb[6];
#pragma unroll
      for (int i = 0; i < 6; ++i) aa[i] = bufA[lk][tx * 6 + i];
#pragma unroll
      for (int j = 0; j < 6; ++j) bb[j] = vtt[lk][ty * 6 + j];
#pragma unroll
      for (int i = 0; i < 6; ++i)
#pragma unroll
        for (int j = 0; j < 6; ++j) acc[i][j] += aa[i] * bb[j];
    }
  }
  __syncthreads();
  if (tx < 15 && ty < 15) {
#pragma unroll
    for (int i = 0; i < 6; ++i)
#pragma unroll
      for (int j = 0; j < 6; ++j) cmt[tx * 6 + i][ty * 6 + j] = acc[i][j] * (1.f / 256.f);
  }
  __syncthreads();

  // ---- Phase 2: M[d][k] ----
  int lane = t & 63;
  int kq = __builtin_amdgcn_readfirstlane(t >> 6);
  int k0 = kq * 45;
  int d0 = lane;
  int d1 = lane + 64;
  int d1c = (d1 < 90) ? d1 : 0;
  float m0[45], m1[45];
#pragma unroll
  for (int j = 0; j < 45; ++j) { m0[j] = 0.f; m1[j] = 0.f; }
#pragma unroll 1
  for (int c = 0; c < 90; ++c) {
    const float* pr = p2t + c * 180 + k0;  // wave-uniform, contiguous
    float v0 = cmt[c][d0];
    float v1 = cmt[c][d1c];
#pragma unroll
    for (int j = 0; j < 45; ++j) {
      float p = pr[j];
      m0[j] += p * v0;
      m1[j] += p * v1;
    }
  }
  float* M0 = M + (size_t)wb * 16200 + d0 * 180 + k0;
#pragma unroll
  for (int j = 0; j < 45; ++j) M0[j] = m0[j];
  if (d1 < 90) {
    float* M1 = M + (size_t)wb * 16200 + d1 * 180 + k0;
#pragma unroll
    for (int j = 0; j < 45; ++j) M1[j] = m1[j];
  }
}

// ========== channel attention B: out[l] += M * v[l]  ========================
// 4 blocks per window, 64 tokens each; lane = token, wave-uniform k-block.
__global__ __launch_bounds__(256, 4) void chupd_kernel(const float* __restrict__ qv,
                                                       const float* __restrict__ M,
                                                       float* __restrict__ out) {
  __shared__ float vt[64][91];  // 23.3 KB
  int bid = blockIdx.x;
  int wb = bid >> 2, grp = bid & 3;
  int b = wb >> 8, wi = (wb >> 4) & 15, wj = wb & 15;
  int wbase = (b * 256 + wi * 16) * 256 + wj * 16;
  int t = threadIdx.x;

  for (int idx = t; idx < 64 * 90; idx += 256) {
    int l = idx / 90, d = idx - l * 90;
    int gl = grp * 64 + l;
    int pa = (wbase + (gl >> 4) * 256 + (gl & 15)) * 180;
    vt[l][d] = qv[pa + 90 + d];
  }
  __syncthreads();

  int l = t & 63;
  int kq = __builtin_amdgcn_readfirstlane(t >> 6);
  int k0 = kq * 45;
  const float* Mw = M + (size_t)wb * 16200;
  float pacc[45];
#pragma unroll
  for (int j = 0; j < 45; ++j) pacc[j] = 0.f;
#pragma unroll 1
  for (int d = 0; d < 90; ++d) {
    const float* mr = Mw + d * 180 + k0;  // wave-uniform, contiguous
    float vl = vt[l][d];
#pragma unroll
    for (int j = 0; j < 45; ++j) pacc[j] += mr[j] * vl;
  }
  int gl = grp * 64 + l;
  int pa = (wbase + (gl >> 4) * 256 + (gl & 15)) * 180 + k0;
#pragma unroll
  for (int j = 0; j < 45; ++j) out[pa + j] += pacc[j];
}

// ============================== launcher ====================================
extern "C" void kernel_launch(void* const* d_in, const int* in_sizes, int n_in,
                              void* d_out, int out_size, void* d_ws, size_t ws_size,
                              hipStream_t stream) {
  (void)in_sizes; (void)n_in; (void)out_size; (void)ws_size;
  const float* x   = (const float*)d_in[0];
  const float* w1  = (const float*)d_in[1];
  const float* b1  = (const float*)d_in[2];
  const float* w2  = (const float*)d_in[3];
  const float* b2  = (const float*)d_in[4];
  const float* w3  = (const float*)d_in[5];
  const float* b3  = (const float*)d_in[6];
  const float* wl  = (const float*)d_in[7];
  const float* bl  = (const float*)d_in[8];
  const float* slw = (const float*)d_in[9];
  const float* slb = (const float*)d_in[10];
  const float* pw0 = (const float*)d_in[11];
  const float* pb0 = (const float*)d_in[12];
  const float* g1  = (const float*)d_in[13];
  const float* be1 = (const float*)d_in[14];
  const float* mw1 = (const float*)d_in[15];
  const float* mb1 = (const float*)d_in[16];
  const float* g2  = (const float*)d_in[17];
  const float* be2 = (const float*)d_in[18];
  const float* mw2 = (const float*)d_in[19];
  const float* mb2 = (const float*)d_in[20];
  const float* g3  = (const float*)d_in[21];
  const float* be3 = (const float*)d_in[22];
  const float* mw3 = (const float*)d_in[23];
  const float* mb3 = (const float*)d_in[24];
  const float* pjw = (const float*)d_in[25];
  const float* pjb = (const float*)d_in[26];
  float* out = (float*)d_out;
  float* ws  = (float*)d_ws;

  float* qv  = ws;                      // 47185920 floats
  float* t1  = ws + 47185920;           // 9437184
  float* t2  = t1 + 9437184;            // 9437184
  float* pos = t2 + 9437184;            // 5766 (padded to 5768)
  float* rpb = pos + 5768;              // 98304
  // M reuses t1+t2 region (dead after dfe3): 1024*16200 = 16,588,800 floats
  float* M   = t1;
  // p2t lives in the tail of the t1+t2 region (beyond M): 16200 floats
  float* p2t = t1 + 18874368 - 16384;

  pos_mlp_kernel<<<4, 256, 0, stream>>>(pw0, pb0, g1, be1, mw1, mb1,
                                        g2, be2, mw2, mb2, g3, be3, mw3, mb3, pos);
  rpb_kernel<<<384, 256, 0, stream>>>(pos, rpb);
  dfe1_kernel<<<1024, 256, 0, stream>>>(x, w1, b1, t1);
  dfe2_kernel<<<1024, 256, 0, stream>>>(t1, w2, b2, t2);
  dfe3_kernel<<<4096, 256, 0, stream>>>(x, t2, w3, b3, wl, bl, qv);
  p2t_kernel<<<64, 256, 0, stream>>>(pjw, p2t);  // after dfe3: overwrites t2 tail
  att_sp_kernel<<<1024, 256, 0, stream>>>(qv, slw, slb, rpb, pjw, pjb, out);
  cmapM_kernel<<<1024, 256, 0, stream>>>(qv, p2t, M);
  chupd_kernel<<<4096, 256, 0, stream>>>(qv, M, out);
}